// Round 14
// baseline (397.414 us; speedup 1.0000x reference)
//
#include <hip/hip_runtime.h>
#include <hip/hip_bf16.h>

using bf16 = __bf16;
typedef __bf16 bf16x4 __attribute__((ext_vector_type(4)));
typedef __bf16 bf16x8 __attribute__((ext_vector_type(8)));
typedef float f32x4 __attribute__((ext_vector_type(4)));

static constexpr int BATCH = 4;
static constexpr int SEQ   = 2048;
static constexpr int DIN   = 512;
static constexpr int NHEAD = 8;
static constexpr int DMID  = 2048;
static constexpr int MROWS = BATCH * SEQ;   // 8192

// ---------------------------------------------------------------------------
// Mask nonzero check (bitwise OR; flag pre-zeroed via hipMemsetAsync).
// ---------------------------------------------------------------------------
__global__ __launch_bounds__(256) void mask_check(const uint4* __restrict__ m,
                                                  int* __restrict__ flag)
{
    const int base = (blockIdx.x * 256 + threadIdx.x) * 4;
    unsigned nz = 0;
    for (int i = 0; i < 4; ++i) {
        const uint4 v = m[base + i];
        nz |= v.x | v.y | v.z | v.w;
    }
    if (nz) atomicOr(flag, 1);
}

// ---------------------------------------------------------------------------
// All six weight transposes (fp32 [R][C] -> bf16 [C][R]) in ONE launch.
// ---------------------------------------------------------------------------
__global__ __launch_bounds__(256) void transpose_weights(
    const float* __restrict__ WQ, const float* __restrict__ WK,
    const float* __restrict__ WV, const float* __restrict__ WO,
    const float* __restrict__ W1, const float* __restrict__ W2,
    bf16* __restrict__ WQt, bf16* __restrict__ WKt, bf16* __restrict__ WVt,
    bf16* __restrict__ WOt, bf16* __restrict__ W1t, bf16* __restrict__ W2t)
{
    __shared__ float tile[32][33];
    const int bid = blockIdx.x;
    const float* in; bf16* out; int ip, op, cx, ry;
    if (bid < 1024) {
        const int w = bid >> 8, idx = bid & 255;
        in  = w == 0 ? WQ  : w == 1 ? WK  : w == 2 ? WV  : WO;
        out = w == 0 ? WQt : w == 1 ? WKt : w == 2 ? WVt : WOt;
        ip = 512; op = 512; cx = idx & 15; ry = idx >> 4;
    } else if (bid < 2048) {
        const int idx = bid - 1024;
        in = W1; out = W1t; ip = 2048; op = 512; cx = idx & 63; ry = idx >> 6;
    } else {
        const int idx = bid - 2048;
        in = W2; out = W2t; ip = 512; op = 2048; cx = idx & 15; ry = idx >> 4;
    }
    const int c0 = cx * 32, r0 = ry * 32;
    const int tx = threadIdx.x & 31, ty = threadIdx.x >> 5;
    for (int i = 0; i < 32; i += 8)
        tile[ty + i][tx] = in[(size_t)(r0 + ty + i) * ip + c0 + tx];
    __syncthreads();
    for (int i = 0; i < 32; i += 8)
        out[(size_t)(c0 + ty + i) * op + r0 + tx] = (bf16)tile[tx][ty + i];
}

// ---------------------------------------------------------------------------
// bf16 [R][C] -> bf16 transposed [C][R].  Grid (C/32, R/32).
// ---------------------------------------------------------------------------
__global__ __launch_bounds__(256) void transpose_b2b(const bf16* __restrict__ in,
                                                     bf16* __restrict__ out,
                                                     int ip, int op)
{
    __shared__ bf16 tile[32][33];
    const int c0 = blockIdx.x * 32;
    const int r0 = blockIdx.y * 32;
    const int tx = threadIdx.x & 31;
    const int ty = threadIdx.x >> 5;
    for (int i = 0; i < 32; i += 8)
        tile[ty + i][tx] = in[(size_t)(r0 + ty + i) * ip + c0 + tx];
    __syncthreads();
    for (int i = 0; i < 32; i += 8)
        out[(size_t)(c0 + ty + i) * op + r0 + tx] = tile[tx][ty + i];
}

// ---------------------------------------------------------------------------
// A-streaming "skinny" GEMM: C[M,N] = act(A[M,K] @ Bt[N,K]^T).
// Block = 32 rows x 256 cols, BK=64. A fetched N/256 times; Bt L2-resident.
// ---------------------------------------------------------------------------
template <int ACT>
__global__ __launch_bounds__(256) void gemm_skinny(const bf16* __restrict__ A,
                                                   const bf16* __restrict__ Bt,
                                                   bf16* __restrict__ C,
                                                   int M, int N, int K)
{
    __shared__ bf16 sA[32 * 72];
    __shared__ bf16 sB[256 * 72];

    const int t    = threadIdx.x;
    const int lane = t & 63;
    const int wave = t >> 6;
    const int wm   = wave >> 1;
    const int wn   = wave & 1;
    const int lr   = lane & 15;
    const int lq   = lane >> 4;

    const int m0 = blockIdx.y * 32;
    const int n0 = blockIdx.x * 256;

    const int ar = t >> 3;           // 0..31
    const int ac = (t & 7) * 8;      // 0..56

    f32x4 acc[8] = {};

    for (int k0 = 0; k0 < K; k0 += 64) {
        int4 av = *reinterpret_cast<const int4*>(A + (size_t)(m0 + ar) * K + k0 + ac);
        int4 bv[8];
        for (int i = 0; i < 8; ++i)
            bv[i] = *reinterpret_cast<const int4*>(Bt + (size_t)(n0 + i * 32 + ar) * K + k0 + ac);

        *reinterpret_cast<int4*>(&sA[ar * 72 + ac]) = av;
        for (int i = 0; i < 8; ++i)
            *reinterpret_cast<int4*>(&sB[(i * 32 + ar) * 72 + ac]) = bv[i];
        __syncthreads();

        for (int kk = 0; kk < 2; ++kk) {
            bf16x8 af = *reinterpret_cast<const bf16x8*>(&sA[(wm * 16 + lr) * 72 + kk * 32 + lq * 8]);
            for (int ni = 0; ni < 8; ++ni) {
                bf16x8 bfr = *reinterpret_cast<const bf16x8*>(&sB[(wn * 128 + ni * 16 + lr) * 72 + kk * 32 + lq * 8]);
                acc[ni] = __builtin_amdgcn_mfma_f32_16x16x32_bf16(af, bfr, acc[ni], 0, 0, 0);
            }
        }
        __syncthreads();
    }

    for (int ni = 0; ni < 8; ++ni) {
        const int col = n0 + wn * 128 + ni * 16 + lr;
        for (int j = 0; j < 4; ++j) {
            const int row = m0 + wm * 16 + lq * 4 + j;
            float v = acc[ni][j];
            if (ACT == 1) v = v > 0.f ? v : 0.f;
            C[(size_t)row * N + col] = (bf16)v;
        }
    }
}

// ---------------------------------------------------------------------------
// QKV projection: gemm_skinny with fp32 A (cast fused into staging).
// ---------------------------------------------------------------------------
__device__ inline int4 cvt16(const float* p)
{
    const float4 f0 = *reinterpret_cast<const float4*>(p);
    const float4 f1 = *reinterpret_cast<const float4*>(p + 4);
    bf16x8 r;
    r[0] = (bf16)f0.x; r[1] = (bf16)f0.y; r[2] = (bf16)f0.z; r[3] = (bf16)f0.w;
    r[4] = (bf16)f1.x; r[5] = (bf16)f1.y; r[6] = (bf16)f1.z; r[7] = (bf16)f1.w;
    return *reinterpret_cast<int4*>(&r);
}

__global__ __launch_bounds__(256) void gemm_qkv(const float* __restrict__ q,
                                                const float* __restrict__ k,
                                                const float* __restrict__ v,
                                                const bf16* __restrict__ WQt,
                                                const bf16* __restrict__ WKt,
                                                const bf16* __restrict__ WVt,
                                                bf16* __restrict__ Qb,
                                                bf16* __restrict__ Kb,
                                                bf16* __restrict__ Vb)
{
    const float* A  = blockIdx.z == 0 ? q   : blockIdx.z == 1 ? k   : v;
    const bf16*  Bt = blockIdx.z == 0 ? WQt : blockIdx.z == 1 ? WKt : WVt;
    bf16*        C  = blockIdx.z == 0 ? Qb  : blockIdx.z == 1 ? Kb  : Vb;
    const int K = DIN, N = DIN;

    __shared__ bf16 sA[32 * 72];
    __shared__ bf16 sB[256 * 72];

    const int t    = threadIdx.x;
    const int lane = t & 63;
    const int wave = t >> 6;
    const int wm   = wave >> 1;
    const int wn   = wave & 1;
    const int lr   = lane & 15;
    const int lq   = lane >> 4;

    const int m0 = blockIdx.y * 32;
    const int n0 = blockIdx.x * 256;

    const int ar = t >> 3;
    const int ac = (t & 7) * 8;

    f32x4 acc[8] = {};

    for (int k0 = 0; k0 < K; k0 += 64) {
        int4 av = cvt16(A + (size_t)(m0 + ar) * K + k0 + ac);
        int4 bv[8];
        for (int i = 0; i < 8; ++i)
            bv[i] = *reinterpret_cast<const int4*>(Bt + (size_t)(n0 + i * 32 + ar) * K + k0 + ac);

        *reinterpret_cast<int4*>(&sA[ar * 72 + ac]) = av;
        for (int i = 0; i < 8; ++i)
            *reinterpret_cast<int4*>(&sB[(i * 32 + ar) * 72 + ac]) = bv[i];
        __syncthreads();

        for (int kk = 0; kk < 2; ++kk) {
            bf16x8 af = *reinterpret_cast<const bf16x8*>(&sA[(wm * 16 + lr) * 72 + kk * 32 + lq * 8]);
            for (int ni = 0; ni < 8; ++ni) {
                bf16x8 bfr = *reinterpret_cast<const bf16x8*>(&sB[(wn * 128 + ni * 16 + lr) * 72 + kk * 32 + lq * 8]);
                acc[ni] = __builtin_amdgcn_mfma_f32_16x16x32_bf16(af, bfr, acc[ni], 0, 0, 0);
            }
        }
        __syncthreads();
    }

    for (int ni = 0; ni < 8; ++ni) {
        const int col = n0 + wn * 128 + ni * 16 + lr;
        for (int j = 0; j < 4; ++j) {
            const int row = m0 + wm * 16 + lq * 4 + j;
            C[(size_t)row * N + col] = (bf16)acc[ni][j];
        }
    }
}

// ---------------------------------------------------------------------------
// Flash attention (MFMA), q-tile 128 (2x MFMA per staged K/V tile vs q-64):
// each wave owns rows [w*16,w*16+16) and [64+w*16, 64+w*16+16). Max-free
// softmax, runtime mask-skip, rowsum via P . ones. LDS 53 KB -> 2 blk/CU.
// ---------------------------------------------------------------------------
__global__ __launch_bounds__(256) void attn_kernel(const bf16* __restrict__ Qb,
                                                   const bf16* __restrict__ Kb,
                                                   const bf16* __restrict__ Vt,
                                                   const float* __restrict__ mask,
                                                   bf16* __restrict__ O,
                                                   const int* __restrict__ mzf)
{
    const int qt = blockIdx.x;
    const int h  = blockIdx.y;
    const int b  = blockIdx.z;

    const int t    = threadIdx.x;
    const int lane = t & 63;
    const int wave = t >> 6;
    const int lr   = lane & 15;
    const int lq   = lane >> 4;
    const int q0   = qt * 128;
    const bool useM = (*mzf != 0);

    __shared__ bf16 sK[64 * 72];
    __shared__ bf16 sV[64 * 72];
    __shared__ bf16 sP[4][32 * 72];     // per-wave P: rows g*16 + r
    __shared__ bf16 sM[128 * 68];       // mask * log2e (only if useM)

    bf16x8 qf[2][2];
    for (int g = 0; g < 2; ++g) {
        const int qrow = q0 + g * 64 + wave * 16 + lr;
        const bf16* qp = Qb + (size_t)(b * SEQ + qrow) * DIN + h * 64 + lq * 8;
        qf[g][0] = *reinterpret_cast<const bf16x8*>(qp);
        qf[g][1] = *reinterpret_cast<const bf16x8*>(qp + 32);
    }

    f32x4 o[2][4] = {};
    f32x4 lrow[2] = {};

    const int sr = t >> 2;
    const int sc = (t & 3) << 3;

    const bf16*  kbase = Kb + (size_t)(b * SEQ) * DIN + h * 64;
    const bf16*  vbase = Vt + (size_t)(h * 64 + sr) * MROWS + b * SEQ;
    const float* mbase = mask + ((size_t)b * SEQ + q0) * SEQ;

    constexpr float L2E = 1.4426950408889634f;
    constexpr float SCL = 0.125f * L2E;
    const bf16x8 ones = {(bf16)1.f, (bf16)1.f, (bf16)1.f, (bf16)1.f,
                         (bf16)1.f, (bf16)1.f, (bf16)1.f, (bf16)1.f};

    for (int tile = 0; tile < SEQ / 64; ++tile) {
        const int k0 = tile * 64;
        if (tile) __syncthreads();

        {
            int4 kr0 = *reinterpret_cast<const int4*>(kbase + (size_t)(k0 + sr) * DIN + sc);
            int4 kr1 = *reinterpret_cast<const int4*>(kbase + (size_t)(k0 + sr) * DIN + sc + 32);
            int4 vr0 = *reinterpret_cast<const int4*>(vbase + k0 + sc);
            int4 vr1 = *reinterpret_cast<const int4*>(vbase + k0 + sc + 32);
            *reinterpret_cast<int4*>(&sK[sr * 72 + sc])      = kr0;
            *reinterpret_cast<int4*>(&sK[sr * 72 + sc + 32]) = kr1;
            *reinterpret_cast<int4*>(&sV[sr * 72 + sc])      = vr0;
            *reinterpret_cast<int4*>(&sV[sr * 72 + sc + 32]) = vr1;
            if (useM) {
                for (int i = 0; i < 8; ++i) {
                    const int idx = t + 256 * i;
                    const float4 mr = *reinterpret_cast<const float4*>(
                        mbase + (size_t)(idx >> 4) * SEQ + k0 + (idx & 15) * 4);
                    bf16x4 mv;
                    mv[0] = (bf16)(mr.x * L2E); mv[1] = (bf16)(mr.y * L2E);
                    mv[2] = (bf16)(mr.z * L2E); mv[3] = (bf16)(mr.w * L2E);
                    *reinterpret_cast<bf16x4*>(&sM[(idx >> 4) * 68 + (idx & 15) * 4]) = mv;
                }
            }
        }
        __syncthreads();

        for (int g = 0; g < 2; ++g) {
            // S = Q K^T  (16 x 64 per wave per group)
            f32x4 sf[4] = {};
            for (int s = 0; s < 2; ++s) {
                const bf16x8 qfr = qf[g][s];
                for (int ni = 0; ni < 4; ++ni) {
                    bf16x8 kf = *reinterpret_cast<const bf16x8*>(&sK[(ni * 16 + lr) * 72 + s * 32 + lq * 8]);
                    sf[ni] = __builtin_amdgcn_mfma_f32_16x16x32_bf16(qfr, kf, sf[ni], 0, 0, 0);
                }
            }

            // P = exp2(S*scl [+ m]) straight to LDS (A-layout)
            if (useM) {
                for (int j = 0; j < 4; ++j) {
                    const int mr2 = (g * 64 + wave * 16 + lq * 4 + j) * 68;
                    for (int ni = 0; ni < 4; ++ni) {
                        const float mval = (float)sM[mr2 + ni * 16 + lr];
                        sP[wave][(g * 16 + lq * 4 + j) * 72 + ni * 16 + lr] = (bf16)exp2f(sf[ni][j] * SCL + mval);
                    }
                }
            } else {
                for (int j = 0; j < 4; ++j)
                    for (int ni = 0; ni < 4; ++ni)
                        sP[wave][(g * 16 + lq * 4 + j) * 72 + ni * 16 + lr] = (bf16)exp2f(sf[ni][j] * SCL);
            }
        }

        // O += P V; row sums via P . ones (both groups)
        for (int g = 0; g < 2; ++g) {
            f32x4 rs = {};
            for (int s = 0; s < 2; ++s) {
                bf16x8 pf = *reinterpret_cast<const bf16x8*>(&sP[wave][(g * 16 + lr) * 72 + s * 32 + lq * 8]);
                rs = __builtin_amdgcn_mfma_f32_16x16x32_bf16(pf, ones, rs, 0, 0, 0);
                for (int ni = 0; ni < 4; ++ni) {
                    bf16x8 vf = *reinterpret_cast<const bf16x8*>(&sV[(ni * 16 + lr) * 72 + s * 32 + lq * 8]);
                    o[g][ni] = __builtin_amdgcn_mfma_f32_16x16x32_bf16(pf, vf, o[g][ni], 0, 0, 0);
                }
            }
            for (int j = 0; j < 4; ++j)
                lrow[g][j] += rs[j];
        }
    }

    for (int g = 0; g < 2; ++g)
        for (int ni = 0; ni < 4; ++ni)
            for (int j = 0; j < 4; ++j) {
                const int row = q0 + g * 64 + wave * 16 + lq * 4 + j;
                const int col = h * 64 + ni * 16 + lr;
                O[(size_t)(b * SEQ + row) * DIN + col] = (bf16)(o[g][ni][j] / lrow[g][j]);
            }
}

// ---------------------------------------------------------------------------
// Fused residual add + LayerNorm over D=512. X fp32, Y bf16.
// ---------------------------------------------------------------------------
__global__ __launch_bounds__(256) void add_ln(const float* __restrict__ X,
                                              const bf16* __restrict__ Y,
                                              bf16* __restrict__ Ob,
                                              float* __restrict__ Of)
{
    const int row  = blockIdx.x * 4 + (threadIdx.x >> 6);
    const int lane = threadIdx.x & 63;
    const size_t base = (size_t)row * DIN + lane * 8;
    const float4 x0 = *reinterpret_cast<const float4*>(X + base);
    const float4 x1 = *reinterpret_cast<const float4*>(X + base + 4);
    const bf16x8 yv = *reinterpret_cast<const bf16x8*>(Y + base);
    float v[8] = {x0.x, x0.y, x0.z, x0.w, x1.x, x1.y, x1.z, x1.w};
    float s = 0.f;
    for (int i = 0; i < 8; ++i) { v[i] += (float)yv[i]; s += v[i]; }
    for (int off = 1; off < 64; off <<= 1) s += __shfl_xor(s, off);
    const float mu = s * (1.f / DIN);
    float var = 0.f;
    for (int i = 0; i < 8; ++i) { const float d = v[i] - mu; var += d * d; }
    for (int off = 1; off < 64; off <<= 1) var += __shfl_xor(var, off);
    const float rstd = rsqrtf(var * (1.f / DIN) + 1e-5f);
    float r[8];
    for (int i = 0; i < 8; ++i) r[i] = (v[i] - mu) * rstd;
    if (Ob) {
        bf16x8 ov;
        for (int i = 0; i < 8; ++i) ov[i] = (bf16)r[i];
        *reinterpret_cast<bf16x8*>(Ob + base) = ov;
    }
    if (Of) {
        *reinterpret_cast<float4*>(Of + base)     = make_float4(r[0], r[1], r[2], r[3]);
        *reinterpret_cast<float4*>(Of + base + 4) = make_float4(r[4], r[5], r[6], r[7]);
    }
}

// ---------------------------------------------------------------------------
extern "C" void kernel_launch(void* const* d_in, const int* in_sizes, int n_in,
                              void* d_out, int out_size, void* d_ws, size_t ws_size,
                              hipStream_t stream)
{
    const float* query = (const float*)d_in[0];
    const float* key   = (const float*)d_in[1];
    const float* value = (const float*)d_in[2];
    const float* mask  = (const float*)d_in[3];
    const float* WQ    = (const float*)d_in[4];
    const float* WK    = (const float*)d_in[5];
    const float* WV    = (const float*)d_in[6];
    const float* WO    = (const float*)d_in[7];
    const float* W1    = (const float*)d_in[8];
    const float* W2    = (const float*)d_in[9];

    char* w = (char*)d_ws;
    size_t off = 0;
    auto carve2 = [&](size_t elems) { bf16* p = (bf16*)(w + off); off += elems * 2; return p; };
    auto carve4 = [&](size_t elems) { float* p = (float*)(w + off); off += elems * 4; return p; };

    bf16* Qb    = carve2((size_t)MROWS * DIN);
    bf16* Kb    = carve2((size_t)MROWS * DIN);
    bf16* Vb    = carve2((size_t)MROWS * DIN);
    bf16* Vt    = carve2((size_t)MROWS * DIN);
    bf16* Mid   = carve2((size_t)MROWS * DMID);
    float* Ln1f = carve4((size_t)MROWS * DIN);
    bf16* WQt   = carve2((size_t)DIN * DIN);
    bf16* WKt   = carve2((size_t)DIN * DIN);
    bf16* WVt   = carve2((size_t)DIN * DIN);
    bf16* WOt   = carve2((size_t)DIN * DIN);
    bf16* W1t   = carve2((size_t)DIN * DMID);
    bf16* W2t   = carve2((size_t)DMID * DIN);
    int*  mzf   = (int*)(w + off); off += 16;
    if (off > ws_size) return;

    // aliases of dead buffers:
    bf16* Ob   = Vb;   // attn output   (Vb dead after Vt transpose)
    bf16* Two  = Qb;   // WO output     (Qb dead after attention)
    bf16* Ln1b = Kb;   // LN1 bf16      (Kb dead after attention)
    bf16* F2   = Vt;   // FFN output    (Vt dead after attention)

    const dim3 blk(256);

    // mask-zero detection
    hipMemsetAsync(mzf, 0, 4, stream);
    mask_check<<<dim3(4096), blk, 0, stream>>>((const uint4*)mask, mzf);

    // all six weight cast+transposes in one launch
    transpose_weights<<<dim3(3072), blk, 0, stream>>>(WQ, WK, WV, WO, W1, W2,
                                                      WQt, WKt, WVt, WOt, W1t, W2t);

    // Q/K/V projections: A-streaming skinny GEMM, cast fused, one launch
    gemm_qkv<<<dim3(DIN / 256, MROWS / 32, 3), blk, 0, stream>>>(query, key, value,
                                                                 WQt, WKt, WVt, Qb, Kb, Vb);

    // V -> Vt[h*64+d][b*L+l]
    transpose_b2b<<<dim3(DIN / 32, MROWS / 32), blk, 0, stream>>>(Vb, Vt, DIN, MROWS);

    // attention (q-tile 128)
    attn_kernel<<<dim3(SEQ / 128, NHEAD, BATCH), blk, 0, stream>>>(Qb, Kb, Vt, mask, Ob, mzf);

    // output projection + residual + LN (keep fp32 copy for residual 2)
    gemm_skinny<0><<<dim3(DIN / 256, MROWS / 32), blk, 0, stream>>>(Ob, WOt, Two, MROWS, DIN, DIN);
    add_ln<<<dim3(MROWS / 4), blk, 0, stream>>>(query, Two, Ln1b, Ln1f);

    // FFN
    gemm_skinny<1><<<dim3(DMID / 256, MROWS / 32), blk, 0, stream>>>(Ln1b, W1t, Mid, MROWS, DMID, DIN);
    gemm_skinny<0><<<dim3(DIN / 256, MROWS / 32), blk, 0, stream>>>(Mid, W2t, F2, MROWS, DIN, DMID);

    // final residual + LN -> fp32 output
    add_ln<<<dim3(MROWS / 4), blk, 0, stream>>>(Ln1f, F2, (bf16*)nullptr, (float*)d_out);
}

// Round 15
// 392.071 us; speedup vs baseline: 1.0136x; 1.0136x over previous
//
#include <hip/hip_runtime.h>
#include <hip/hip_bf16.h>

using bf16 = __bf16;
typedef __bf16 bf16x4 __attribute__((ext_vector_type(4)));
typedef __bf16 bf16x8 __attribute__((ext_vector_type(8)));
typedef float f32x4 __attribute__((ext_vector_type(4)));

static constexpr int BATCH = 4;
static constexpr int SEQ   = 2048;
static constexpr int DIN   = 512;
static constexpr int NHEAD = 8;
static constexpr int DMID  = 2048;
static constexpr int MROWS = BATCH * SEQ;   // 8192

// ---------------------------------------------------------------------------
// Mask nonzero check (bitwise OR; flag pre-zeroed via hipMemsetAsync).
// ---------------------------------------------------------------------------
__global__ __launch_bounds__(256) void mask_check(const uint4* __restrict__ m,
                                                  int* __restrict__ flag)
{
    const int base = (blockIdx.x * 256 + threadIdx.x) * 4;
    unsigned nz = 0;
    for (int i = 0; i < 4; ++i) {
        const uint4 v = m[base + i];
        nz |= v.x | v.y | v.z | v.w;
    }
    if (nz) atomicOr(flag, 1);
}

// ---------------------------------------------------------------------------
// All six weight transposes (fp32 [R][C] -> bf16 [C][R]) in ONE launch.
// ---------------------------------------------------------------------------
__global__ __launch_bounds__(256) void transpose_weights(
    const float* __restrict__ WQ, const float* __restrict__ WK,
    const float* __restrict__ WV, const float* __restrict__ WO,
    const float* __restrict__ W1, const float* __restrict__ W2,
    bf16* __restrict__ WQt, bf16* __restrict__ WKt, bf16* __restrict__ WVt,
    bf16* __restrict__ WOt, bf16* __restrict__ W1t, bf16* __restrict__ W2t)
{
    __shared__ float tile[32][33];
    const int bid = blockIdx.x;
    const float* in; bf16* out; int ip, op, cx, ry;
    if (bid < 1024) {
        const int w = bid >> 8, idx = bid & 255;
        in  = w == 0 ? WQ  : w == 1 ? WK  : w == 2 ? WV  : WO;
        out = w == 0 ? WQt : w == 1 ? WKt : w == 2 ? WVt : WOt;
        ip = 512; op = 512; cx = idx & 15; ry = idx >> 4;
    } else if (bid < 2048) {
        const int idx = bid - 1024;
        in = W1; out = W1t; ip = 2048; op = 512; cx = idx & 63; ry = idx >> 6;
    } else {
        const int idx = bid - 2048;
        in = W2; out = W2t; ip = 512; op = 2048; cx = idx & 15; ry = idx >> 4;
    }
    const int c0 = cx * 32, r0 = ry * 32;
    const int tx = threadIdx.x & 31, ty = threadIdx.x >> 5;
    for (int i = 0; i < 32; i += 8)
        tile[ty + i][tx] = in[(size_t)(r0 + ty + i) * ip + c0 + tx];
    __syncthreads();
    for (int i = 0; i < 32; i += 8)
        out[(size_t)(c0 + ty + i) * op + r0 + tx] = (bf16)tile[tx][ty + i];
}

// ---------------------------------------------------------------------------
// bf16 [R][C] -> bf16 transposed [C][R].  Grid (C/32, R/32).
// ---------------------------------------------------------------------------
__global__ __launch_bounds__(256) void transpose_b2b(const bf16* __restrict__ in,
                                                     bf16* __restrict__ out,
                                                     int ip, int op)
{
    __shared__ bf16 tile[32][33];
    const int c0 = blockIdx.x * 32;
    const int r0 = blockIdx.y * 32;
    const int tx = threadIdx.x & 31;
    const int ty = threadIdx.x >> 5;
    for (int i = 0; i < 32; i += 8)
        tile[ty + i][tx] = in[(size_t)(r0 + ty + i) * ip + c0 + tx];
    __syncthreads();
    for (int i = 0; i < 32; i += 8)
        out[(size_t)(c0 + ty + i) * op + r0 + tx] = tile[tx][ty + i];
}

// ---------------------------------------------------------------------------
// A-streaming "skinny" GEMM: C[M,N] = act(A[M,K] @ Bt[N,K]^T).
// Block = 32 rows x 256 cols, BK=64. A fetched N/256 times; Bt L2-resident.
// ---------------------------------------------------------------------------
template <int ACT>
__global__ __launch_bounds__(256) void gemm_skinny(const bf16* __restrict__ A,
                                                   const bf16* __restrict__ Bt,
                                                   bf16* __restrict__ C,
                                                   int M, int N, int K)
{
    __shared__ bf16 sA[32 * 72];
    __shared__ bf16 sB[256 * 72];

    const int t    = threadIdx.x;
    const int lane = t & 63;
    const int wave = t >> 6;
    const int wm   = wave >> 1;
    const int wn   = wave & 1;
    const int lr   = lane & 15;
    const int lq   = lane >> 4;

    const int m0 = blockIdx.y * 32;
    const int n0 = blockIdx.x * 256;

    const int ar = t >> 3;           // 0..31
    const int ac = (t & 7) * 8;      // 0..56

    f32x4 acc[8] = {};

    for (int k0 = 0; k0 < K; k0 += 64) {
        int4 av = *reinterpret_cast<const int4*>(A + (size_t)(m0 + ar) * K + k0 + ac);
        int4 bv[8];
        for (int i = 0; i < 8; ++i)
            bv[i] = *reinterpret_cast<const int4*>(Bt + (size_t)(n0 + i * 32 + ar) * K + k0 + ac);

        *reinterpret_cast<int4*>(&sA[ar * 72 + ac]) = av;
        for (int i = 0; i < 8; ++i)
            *reinterpret_cast<int4*>(&sB[(i * 32 + ar) * 72 + ac]) = bv[i];
        __syncthreads();

        for (int kk = 0; kk < 2; ++kk) {
            bf16x8 af = *reinterpret_cast<const bf16x8*>(&sA[(wm * 16 + lr) * 72 + kk * 32 + lq * 8]);
            for (int ni = 0; ni < 8; ++ni) {
                bf16x8 bfr = *reinterpret_cast<const bf16x8*>(&sB[(wn * 128 + ni * 16 + lr) * 72 + kk * 32 + lq * 8]);
                acc[ni] = __builtin_amdgcn_mfma_f32_16x16x32_bf16(af, bfr, acc[ni], 0, 0, 0);
            }
        }
        __syncthreads();
    }

    for (int ni = 0; ni < 8; ++ni) {
        const int col = n0 + wn * 128 + ni * 16 + lr;
        for (int j = 0; j < 4; ++j) {
            const int row = m0 + wm * 16 + lq * 4 + j;
            float v = acc[ni][j];
            if (ACT == 1) v = v > 0.f ? v : 0.f;
            C[(size_t)row * N + col] = (bf16)v;
        }
    }
}

// ---------------------------------------------------------------------------
// QKV projection: gemm_skinny with fp32 A (cast fused into staging).
// ---------------------------------------------------------------------------
__device__ inline int4 cvt16(const float* p)
{
    const float4 f0 = *reinterpret_cast<const float4*>(p);
    const float4 f1 = *reinterpret_cast<const float4*>(p + 4);
    bf16x8 r;
    r[0] = (bf16)f0.x; r[1] = (bf16)f0.y; r[2] = (bf16)f0.z; r[3] = (bf16)f0.w;
    r[4] = (bf16)f1.x; r[5] = (bf16)f1.y; r[6] = (bf16)f1.z; r[7] = (bf16)f1.w;
    return *reinterpret_cast<int4*>(&r);
}

__global__ __launch_bounds__(256) void gemm_qkv(const float* __restrict__ q,
                                                const float* __restrict__ k,
                                                const float* __restrict__ v,
                                                const bf16* __restrict__ WQt,
                                                const bf16* __restrict__ WKt,
                                                const bf16* __restrict__ WVt,
                                                bf16* __restrict__ Qb,
                                                bf16* __restrict__ Kb,
                                                bf16* __restrict__ Vb)
{
    const float* A  = blockIdx.z == 0 ? q   : blockIdx.z == 1 ? k   : v;
    const bf16*  Bt = blockIdx.z == 0 ? WQt : blockIdx.z == 1 ? WKt : WVt;
    bf16*        C  = blockIdx.z == 0 ? Qb  : blockIdx.z == 1 ? Kb  : Vb;
    const int K = DIN, N = DIN;

    __shared__ bf16 sA[32 * 72];
    __shared__ bf16 sB[256 * 72];

    const int t    = threadIdx.x;
    const int lane = t & 63;
    const int wave = t >> 6;
    const int wm   = wave >> 1;
    const int wn   = wave & 1;
    const int lr   = lane & 15;
    const int lq   = lane >> 4;

    const int m0 = blockIdx.y * 32;
    const int n0 = blockIdx.x * 256;

    const int ar = t >> 3;
    const int ac = (t & 7) * 8;

    f32x4 acc[8] = {};

    for (int k0 = 0; k0 < K; k0 += 64) {
        int4 av = cvt16(A + (size_t)(m0 + ar) * K + k0 + ac);
        int4 bv[8];
        for (int i = 0; i < 8; ++i)
            bv[i] = *reinterpret_cast<const int4*>(Bt + (size_t)(n0 + i * 32 + ar) * K + k0 + ac);

        *reinterpret_cast<int4*>(&sA[ar * 72 + ac]) = av;
        for (int i = 0; i < 8; ++i)
            *reinterpret_cast<int4*>(&sB[(i * 32 + ar) * 72 + ac]) = bv[i];
        __syncthreads();

        for (int kk = 0; kk < 2; ++kk) {
            bf16x8 af = *reinterpret_cast<const bf16x8*>(&sA[(wm * 16 + lr) * 72 + kk * 32 + lq * 8]);
            for (int ni = 0; ni < 8; ++ni) {
                bf16x8 bfr = *reinterpret_cast<const bf16x8*>(&sB[(wn * 128 + ni * 16 + lr) * 72 + kk * 32 + lq * 8]);
                acc[ni] = __builtin_amdgcn_mfma_f32_16x16x32_bf16(af, bfr, acc[ni], 0, 0, 0);
            }
        }
        __syncthreads();
    }

    for (int ni = 0; ni < 8; ++ni) {
        const int col = n0 + wn * 128 + ni * 16 + lr;
        for (int j = 0; j < 4; ++j) {
            const int row = m0 + wm * 16 + lq * 4 + j;
            C[(size_t)row * N + col] = (bf16)acc[ni][j];
        }
    }
}

// ---------------------------------------------------------------------------
// Flash attention (MFMA), q-tile 64, max-free softmax, runtime mask-skip.
// + K/V register prefetch rotation (loads for tile t+1 in flight during
//   compute of tile t; only 16 extra VGPRs, no launch-bounds cap -> no spill;
//   tripwire = WRITE_SIZE must stay 8.2 MB).
// + XCD-aware swizzle: flat grid 1024; all 32 q-tiles of one (b,h) land on
//   one XCD so K/V strips (512 KB/pair, 4 pairs/XCD = 2 MB) stay in its L2.
// Row sums via P . ones MFMA. LDS 36.3 KB -> 4 blk/CU; grid = exactly 4/CU.
// ---------------------------------------------------------------------------
__global__ __launch_bounds__(256) void attn_kernel(const bf16* __restrict__ Qb,
                                                   const bf16* __restrict__ Kb,
                                                   const bf16* __restrict__ Vt,
                                                   const float* __restrict__ mask,
                                                   bf16* __restrict__ O,
                                                   const int* __restrict__ mzf)
{
    // XCD swizzle: consecutive blockIdx round-robin across 8 XCDs (heuristic)
    const int bi   = blockIdx.x;
    const int xcd  = bi & 7;
    const int slot = bi >> 3;                 // 0..127
    const int pair = xcd * 4 + (slot >> 5);   // 0..31  (4 pairs per XCD)
    const int qt   = slot & 31;               // 0..31
    const int h    = pair >> 2;
    const int b    = pair & 3;

    const int t    = threadIdx.x;
    const int lane = t & 63;
    const int wave = t >> 6;
    const int lr   = lane & 15;
    const int lq   = lane >> 4;
    const int q0   = qt * 64;
    const bool useM = (*mzf != 0);

    __shared__ bf16 sK[64 * 72];
    __shared__ bf16 sV[64 * 72];
    __shared__ bf16 sP[4][16 * 72];
    __shared__ bf16 sM[64 * 68];

    const int  qrow = q0 + wave * 16 + lr;
    const bf16* qp  = Qb + (size_t)(b * SEQ + qrow) * DIN + h * 64 + lq * 8;
    const bf16x8 qf0 = *reinterpret_cast<const bf16x8*>(qp);
    const bf16x8 qf1 = *reinterpret_cast<const bf16x8*>(qp + 32);

    f32x4 o[4] = {};
    f32x4 lrow = {};

    const int sr = t >> 2;
    const int sc = (t & 3) << 3;

    const bf16*  kbase = Kb + (size_t)(b * SEQ) * DIN + h * 64;
    const bf16*  vbase = Vt + (size_t)(h * 64 + sr) * MROWS + b * SEQ;
    const float* mbase = mask + ((size_t)b * SEQ + q0) * SEQ;

    constexpr float L2E = 1.4426950408889634f;
    constexpr float SCL = 0.125f * L2E;
    const bf16x8 ones = {(bf16)1.f, (bf16)1.f, (bf16)1.f, (bf16)1.f,
                         (bf16)1.f, (bf16)1.f, (bf16)1.f, (bf16)1.f};

    // prefetch tile 0 into registers
    int4 kr0 = *reinterpret_cast<const int4*>(kbase + (size_t)sr * DIN + sc);
    int4 kr1 = *reinterpret_cast<const int4*>(kbase + (size_t)sr * DIN + sc + 32);
    int4 vr0 = *reinterpret_cast<const int4*>(vbase + sc);
    int4 vr1 = *reinterpret_cast<const int4*>(vbase + sc + 32);

    for (int tile = 0; tile < SEQ / 64; ++tile) {
        if (tile) __syncthreads();        // previous compute done reading LDS

        *reinterpret_cast<int4*>(&sK[sr * 72 + sc])      = kr0;
        *reinterpret_cast<int4*>(&sK[sr * 72 + sc + 32]) = kr1;
        *reinterpret_cast<int4*>(&sV[sr * 72 + sc])      = vr0;
        *reinterpret_cast<int4*>(&sV[sr * 72 + sc + 32]) = vr1;
        if (useM) {
            const int k0 = tile * 64;
            for (int i = 0; i < 4; ++i) {
                const int idx = t + 256 * i;
                const float4 mr = *reinterpret_cast<const float4*>(
                    mbase + (size_t)(idx >> 4) * SEQ + k0 + (idx & 15) * 4);
                bf16x4 mv;
                mv[0] = (bf16)(mr.x * L2E); mv[1] = (bf16)(mr.y * L2E);
                mv[2] = (bf16)(mr.z * L2E); mv[3] = (bf16)(mr.w * L2E);
                *reinterpret_cast<bf16x4*>(&sM[(idx >> 4) * 68 + (idx & 15) * 4]) = mv;
            }
        }

        if (tile + 1 < SEQ / 64) {        // issue loads for next tile now
            const int k0 = (tile + 1) * 64;
            kr0 = *reinterpret_cast<const int4*>(kbase + (size_t)(k0 + sr) * DIN + sc);
            kr1 = *reinterpret_cast<const int4*>(kbase + (size_t)(k0 + sr) * DIN + sc + 32);
            vr0 = *reinterpret_cast<const int4*>(vbase + k0 + sc);
            vr1 = *reinterpret_cast<const int4*>(vbase + k0 + sc + 32);
        }
        __syncthreads();

        // S = Q K^T  (16 x 64 per wave)
        f32x4 sf[4] = {};
        for (int s = 0; s < 2; ++s) {
            const bf16x8 qf = s ? qf1 : qf0;
            for (int ni = 0; ni < 4; ++ni) {
                bf16x8 kf = *reinterpret_cast<const bf16x8*>(&sK[(ni * 16 + lr) * 72 + s * 32 + lq * 8]);
                sf[ni] = __builtin_amdgcn_mfma_f32_16x16x32_bf16(qf, kf, sf[ni], 0, 0, 0);
            }
        }

        // P = exp2(S*scl [+ m]) straight to LDS (A-layout)
        if (useM) {
            for (int j = 0; j < 4; ++j) {
                const int mr2 = (wave * 16 + lq * 4 + j) * 68;
                for (int ni = 0; ni < 4; ++ni) {
                    const float mval = (float)sM[mr2 + ni * 16 + lr];
                    sP[wave][(lq * 4 + j) * 72 + ni * 16 + lr] = (bf16)exp2f(sf[ni][j] * SCL + mval);
                }
            }
        } else {
            for (int j = 0; j < 4; ++j)
                for (int ni = 0; ni < 4; ++ni)
                    sP[wave][(lq * 4 + j) * 72 + ni * 16 + lr] = (bf16)exp2f(sf[ni][j] * SCL);
        }

        // O += P V; row sums via P . ones
        f32x4 rs = {};
        for (int s = 0; s < 2; ++s) {
            bf16x8 pf = *reinterpret_cast<const bf16x8*>(&sP[wave][lr * 72 + s * 32 + lq * 8]);
            rs = __builtin_amdgcn_mfma_f32_16x16x32_bf16(pf, ones, rs, 0, 0, 0);
            for (int ni = 0; ni < 4; ++ni) {
                bf16x8 vf = *reinterpret_cast<const bf16x8*>(&sV[(ni * 16 + lr) * 72 + s * 32 + lq * 8]);
                o[ni] = __builtin_amdgcn_mfma_f32_16x16x32_bf16(pf, vf, o[ni], 0, 0, 0);
            }
        }
        for (int j = 0; j < 4; ++j)
            lrow[j] += rs[j];
    }

    for (int ni = 0; ni < 4; ++ni)
        for (int j = 0; j < 4; ++j) {
            const int row = q0 + wave * 16 + lq * 4 + j;
            const int col = h * 64 + ni * 16 + lr;
            O[(size_t)(b * SEQ + row) * DIN + col] = (bf16)(o[ni][j] / lrow[j]);
        }
}

// ---------------------------------------------------------------------------
// Fused residual add + LayerNorm over D=512. X fp32, Y bf16.
// ---------------------------------------------------------------------------
__global__ __launch_bounds__(256) void add_ln(const float* __restrict__ X,
                                              const bf16* __restrict__ Y,
                                              bf16* __restrict__ Ob,
                                              float* __restrict__ Of)
{
    const int row  = blockIdx.x * 4 + (threadIdx.x >> 6);
    const int lane = threadIdx.x & 63;
    const size_t base = (size_t)row * DIN + lane * 8;
    const float4 x0 = *reinterpret_cast<const float4*>(X + base);
    const float4 x1 = *reinterpret_cast<const float4*>(X + base + 4);
    const bf16x8 yv = *reinterpret_cast<const bf16x8*>(Y + base);
    float v[8] = {x0.x, x0.y, x0.z, x0.w, x1.x, x1.y, x1.z, x1.w};
    float s = 0.f;
    for (int i = 0; i < 8; ++i) { v[i] += (float)yv[i]; s += v[i]; }
    for (int off = 1; off < 64; off <<= 1) s += __shfl_xor(s, off);
    const float mu = s * (1.f / DIN);
    float var = 0.f;
    for (int i = 0; i < 8; ++i) { const float d = v[i] - mu; var += d * d; }
    for (int off = 1; off < 64; off <<= 1) var += __shfl_xor(var, off);
    const float rstd = rsqrtf(var * (1.f / DIN) + 1e-5f);
    float r[8];
    for (int i = 0; i < 8; ++i) r[i] = (v[i] - mu) * rstd;
    if (Ob) {
        bf16x8 ov;
        for (int i = 0; i < 8; ++i) ov[i] = (bf16)r[i];
        *reinterpret_cast<bf16x8*>(Ob + base) = ov;
    }
    if (Of) {
        *reinterpret_cast<float4*>(Of + base)     = make_float4(r[0], r[1], r[2], r[3]);
        *reinterpret_cast<float4*>(Of + base + 4) = make_float4(r[4], r[5], r[6], r[7]);
    }
}

// ---------------------------------------------------------------------------
extern "C" void kernel_launch(void* const* d_in, const int* in_sizes, int n_in,
                              void* d_out, int out_size, void* d_ws, size_t ws_size,
                              hipStream_t stream)
{
    const float* query = (const float*)d_in[0];
    const float* key   = (const float*)d_in[1];
    const float* value = (const float*)d_in[2];
    const float* mask  = (const float*)d_in[3];
    const float* WQ    = (const float*)d_in[4];
    const float* WK    = (const float*)d_in[5];
    const float* WV    = (const float*)d_in[6];
    const float* WO    = (const float*)d_in[7];
    const float* W1    = (const float*)d_in[8];
    const float* W2    = (const float*)d_in[9];

    char* w = (char*)d_ws;
    size_t off = 0;
    auto carve2 = [&](size_t elems) { bf16* p = (bf16*)(w + off); off += elems * 2; return p; };
    auto carve4 = [&](size_t elems) { float* p = (float*)(w + off); off += elems * 4; return p; };

    bf16* Qb    = carve2((size_t)MROWS * DIN);
    bf16* Kb    = carve2((size_t)MROWS * DIN);
    bf16* Vb    = carve2((size_t)MROWS * DIN);
    bf16* Vt    = carve2((size_t)MROWS * DIN);
    bf16* Mid   = carve2((size_t)MROWS * DMID);
    float* Ln1f = carve4((size_t)MROWS * DIN);
    bf16* WQt   = carve2((size_t)DIN * DIN);
    bf16* WKt   = carve2((size_t)DIN * DIN);
    bf16* WVt   = carve2((size_t)DIN * DIN);
    bf16* WOt   = carve2((size_t)DIN * DIN);
    bf16* W1t   = carve2((size_t)DIN * DMID);
    bf16* W2t   = carve2((size_t)DMID * DIN);
    int*  mzf   = (int*)(w + off); off += 16;
    if (off > ws_size) return;

    // aliases of dead buffers:
    bf16* Ob   = Vb;   // attn output   (Vb dead after Vt transpose)
    bf16* Two  = Qb;   // WO output     (Qb dead after attention)
    bf16* Ln1b = Kb;   // LN1 bf16      (Kb dead after attention)
    bf16* F2   = Vt;   // FFN output    (Vt dead after attention)

    const dim3 blk(256);

    // mask-zero detection
    hipMemsetAsync(mzf, 0, 4, stream);
    mask_check<<<dim3(4096), blk, 0, stream>>>((const uint4*)mask, mzf);

    // all six weight cast+transposes in one launch
    transpose_weights<<<dim3(3072), blk, 0, stream>>>(WQ, WK, WV, WO, W1, W2,
                                                      WQt, WKt, WVt, WOt, W1t, W2t);

    // Q/K/V projections: A-streaming skinny GEMM, cast fused, one launch
    gemm_qkv<<<dim3(DIN / 256, MROWS / 32, 3), blk, 0, stream>>>(query, key, value,
                                                                 WQt, WKt, WVt, Qb, Kb, Vb);

    // V -> Vt[h*64+d][b*L+l]
    transpose_b2b<<<dim3(DIN / 32, MROWS / 32), blk, 0, stream>>>(Vb, Vt, DIN, MROWS);

    // attention (q-tile 64, XCD-swizzled flat grid, K/V prefetch)
    attn_kernel<<<dim3(1024), blk, 0, stream>>>(Qb, Kb, Vt, mask, Ob, mzf);

    // output projection + residual + LN (keep fp32 copy for residual 2)
    gemm_skinny<0><<<dim3(DIN / 256, MROWS / 32), blk, 0, stream>>>(Ob, WOt, Two, MROWS, DIN, DIN);
    add_ln<<<dim3(MROWS / 4), blk, 0, stream>>>(query, Two, Ln1b, Ln1f);

    // FFN
    gemm_skinny<1><<<dim3(DMID / 256, MROWS / 32), blk, 0, stream>>>(Ln1b, W1t, Mid, MROWS, DMID, DIN);
    gemm_skinny<0><<<dim3(DIN / 256, MROWS / 32), blk, 0, stream>>>(Mid, W2t, F2, MROWS, DIN, DMID);

    // final residual + LN -> fp32 output
    add_ln<<<dim3(MROWS / 4), blk, 0, stream>>>(Ln1f, F2, (bf16*)nullptr, (float*)d_out);
}